// Round 17
// baseline (36.897 us; speedup 1.0000x reference)
//
#include <hip/hip_runtime.h>
#include <hip/hip_bf16.h>

// Problem constants (match reference setup_inputs)
#define BB 64
#define SS 512
#define DD 1024
#define VV 64
#define NSEG (BB * SS)        // 32768
#define THREADS 512
#define WPB (THREADS / 64)    // 8 waves per block
#define GRID (NSEG / (WPB * 2))  // 2048 blocks: blockIdx = (bg<<9) | s, bg in 0..3

typedef float f32x4 __attribute__((ext_vector_type(4)));

// ---------- Pass A: segment start offsets from sorted segment_ids ----------
__global__ __launch_bounds__(256) void fill_bounds_kernel(
    const int* __restrict__ seg_ids,
    int* __restrict__ seg_start,
    int T)
{
    int t = blockIdx.x * blockDim.x + threadIdx.x;
    if (t >= T) return;
    int cur  = seg_ids[t];
    int prev = (t == 0) ? -1 : seg_ids[t - 1];
    for (int s = prev + 1; s <= cur; ++s) seg_start[s] = t;
    if (t == T - 1) {
        for (int s = cur + 1; s <= NSEG; ++s) seg_start[s] = T;
    }
}

// ---------- Pass B: R14 structure, TWO segments per wave (fused gathers) ----------
// Single variable vs R14: each wave owns segments (b, s) and (b+1, s) — same pos
// row, adjacent batches. Gather loops fused with wave-uniform guards -> 32 loads
// in flight per vmcnt wait (R14: 16), half the waves, half the per-seg chain-head
// cost. Bytes, VMEM instrs/seg, store pattern identical to R14.
__global__ __launch_bounds__(THREADS) void seg_mean_2w_kernel(
    const int* __restrict__ tokens,
    const int* __restrict__ seg_start,  // [NSEG+1]
    const float* __restrict__ emb,      // [V, D]
    const float* __restrict__ pos,      // [S, D]
    float* __restrict__ out)            // [B*S, D]
{
    __shared__ float s_pos[DD];         // 4 KB: the block's shared pos row

    const int tid = threadIdx.x;
    const int bg  = blockIdx.x >> 9;    // 0..3  (group of 16 batches)
    const int s   = blockIdx.x & (SS - 1);

    // stage pos[s] once per block (shared by all 16 segments this block covers)
    if (tid < DD / 4) {
        reinterpret_cast<f32x4*>(s_pos)[tid] =
            reinterpret_cast<const f32x4*>(pos + (size_t)s * DD)[tid];
    }
    __syncthreads();

    const int wave = tid >> 6;
    const int lane = tid & 63;
    // wave-uniform seg ids pinned to SGPRs -> all control loads on scalar pipe
    const int segA = __builtin_amdgcn_readfirstlane((bg * 16 + wave * 2) * SS + s);
    const int segB = segA + SS;         // next batch, same s
    const int d0   = lane * 4;

    const int loA = seg_start[segA];
    const int hiA = seg_start[segA + 1];
    const int loB = seg_start[segB];
    const int hiB = seg_start[segB + 1];
    const int cA = hiA - loA;
    const int cB = hiB - loB;
    const int cmax = (cA > cB) ? cA : cB;

    f32x4 a0 = (f32x4)(0.f), a1 = (f32x4)(0.f), a2 = (f32x4)(0.f), a3 = (f32x4)(0.f);
    f32x4 b0 = (f32x4)(0.f), b1 = (f32x4)(0.f), b2 = (f32x4)(0.f), b3 = (f32x4)(0.f);

    for (int i = 0; i < cmax; ++i) {
        if (i < cA) {
            const int tok = tokens[loA + i];         // SGPR index -> s_load
            const float* e = emb + (size_t)tok * DD + d0;
            a0 += *reinterpret_cast<const f32x4*>(e);
            a1 += *reinterpret_cast<const f32x4*>(e + 256);
            a2 += *reinterpret_cast<const f32x4*>(e + 512);
            a3 += *reinterpret_cast<const f32x4*>(e + 768);
        }
        if (i < cB) {
            const int tok = tokens[loB + i];         // SGPR index -> s_load
            const float* e = emb + (size_t)tok * DD + d0;
            b0 += *reinterpret_cast<const f32x4*>(e);
            b1 += *reinterpret_cast<const f32x4*>(e + 256);
            b2 += *reinterpret_cast<const f32x4*>(e + 512);
            b3 += *reinterpret_cast<const f32x4*>(e + 768);
        }
    }

    const float invA = (cA > 0) ? (1.0f / (float)cA) : 0.0f;
    const float invB = (cB > 0) ? (1.0f / (float)cB) : 0.0f;

    // pos from LDS (ds_read, shared by both segments)
    const f32x4 p0 = *reinterpret_cast<const f32x4*>(s_pos + d0);
    const f32x4 p1 = *reinterpret_cast<const f32x4*>(s_pos + d0 + 256);
    const f32x4 p2 = *reinterpret_cast<const f32x4*>(s_pos + d0 + 512);
    const f32x4 p3 = *reinterpret_cast<const f32x4*>(s_pos + d0 + 768);

    float* orowA = out + (size_t)segA * DD + d0;
    __builtin_nontemporal_store(a0 * invA + p0, reinterpret_cast<f32x4*>(orowA));
    __builtin_nontemporal_store(a1 * invA + p1, reinterpret_cast<f32x4*>(orowA + 256));
    __builtin_nontemporal_store(a2 * invA + p2, reinterpret_cast<f32x4*>(orowA + 512));
    __builtin_nontemporal_store(a3 * invA + p3, reinterpret_cast<f32x4*>(orowA + 768));

    float* orowB = out + (size_t)segB * DD + d0;
    __builtin_nontemporal_store(b0 * invB + p0, reinterpret_cast<f32x4*>(orowB));
    __builtin_nontemporal_store(b1 * invB + p1, reinterpret_cast<f32x4*>(orowB + 256));
    __builtin_nontemporal_store(b2 * invB + p2, reinterpret_cast<f32x4*>(orowB + 512));
    __builtin_nontemporal_store(b3 * invB + p3, reinterpret_cast<f32x4*>(orowB + 768));
}

// ---------- Fallback (ws too small): binary-search kernel ----------
__device__ __forceinline__ int lower_bound_dev(const int* __restrict__ a, int n, int key) {
    int lo = 0, hi = n;
    while (lo < hi) {
        int mid = (lo + hi) >> 1;
        if (a[mid] < key) lo = mid + 1; else hi = mid;
    }
    return lo;
}

__global__ __launch_bounds__(256) void seg_mean_embed_bsearch_kernel(
    const int* __restrict__ tokens,
    const int* __restrict__ seg_ids,
    const float* __restrict__ emb,
    const float* __restrict__ pos,
    float* __restrict__ out,
    int T)
{
    const int seg = blockIdx.x;
    const int lo = lower_bound_dev(seg_ids, T, seg);
    const int hi = lower_bound_dev(seg_ids, T, seg + 1);
    const int d = threadIdx.x * 4;

    f32x4 acc = (f32x4)(0.f);
    for (int t = lo; t < hi; ++t) {
        const int tok = tokens[t];
        acc += *reinterpret_cast<const f32x4*>(emb + (size_t)tok * DD + d);
    }
    const int cnt = hi - lo;
    const float inv = (cnt > 0) ? (1.0f / (float)cnt) : 0.0f;
    const int s = seg & (SS - 1);
    const f32x4 p = *reinterpret_cast<const f32x4*>(pos + (size_t)s * DD + d);
    f32x4 o = acc * inv + p;
    *reinterpret_cast<f32x4*>(out + (size_t)seg * DD + d) = o;
}

extern "C" void kernel_launch(void* const* d_in, const int* in_sizes, int n_in,
                              void* d_out, int out_size, void* d_ws, size_t ws_size,
                              hipStream_t stream) {
    const int*   tokens  = (const int*)d_in[0];
    const int*   seg_ids = (const int*)d_in[1];
    const float* emb     = (const float*)d_in[2];
    const float* pos     = (const float*)d_in[3];
    float*       out     = (float*)d_out;
    const int T = in_sizes[0];

    const size_t need = (size_t)(NSEG + 1) * sizeof(int);
    if (ws_size >= need) {
        int* seg_start = (int*)d_ws;
        fill_bounds_kernel<<<(T + 255) / 256, 256, 0, stream>>>(seg_ids, seg_start, T);
        seg_mean_2w_kernel<<<GRID, THREADS, 0, stream>>>(tokens, seg_start, emb, pos, out);
    } else {
        seg_mean_embed_bsearch_kernel<<<NSEG, 256, 0, stream>>>(tokens, seg_ids, emb, pos, out, T);
    }
}

// Round 18
// 35.347 us; speedup vs baseline: 1.0438x; 1.0438x over previous
//
#include <hip/hip_runtime.h>
#include <hip/hip_bf16.h>

// Problem constants (match reference setup_inputs)
#define BB 64
#define SS 512
#define DD 1024
#define VV 64
#define NSEG (BB * SS)        // 32768
#define THREADS 1024
#define WPB (THREADS / 64)    // 16 waves per block, one segment per wave
#define GRID (NSEG / WPB)     // 2048 blocks: blockIdx = (bg<<9) | s, bg in 0..3

typedef float f32x4 __attribute__((ext_vector_type(4)));

// ---------- Pass A: segment start offsets from sorted segment_ids ----------
__global__ __launch_bounds__(256) void fill_bounds_kernel(
    const int* __restrict__ seg_ids,
    int* __restrict__ seg_start,
    int T)
{
    int t = blockIdx.x * blockDim.x + threadIdx.x;
    if (t >= T) return;
    int cur  = seg_ids[t];
    int prev = (t == 0) ? -1 : seg_ids[t - 1];
    for (int s = prev + 1; s <= cur; ++s) seg_start[s] = t;
    if (t == T - 1) {
        for (int s = cur + 1; s <= NSEG; ++s) seg_start[s] = T;
    }
}

// ---------- Pass B: R14 body, 1024-thread blocks (16 waves/dispatch) ----------
// Single variable vs R14: block size 512 -> 1024. Each dispatch installs 16
// waves (vs 8), halving block-retirement rate the CP must backfill; pos-LDS
// staging amortized over 16 segments (vs 8). Gather, scalar control loads,
// NT store stream identical to R14.
__global__ __launch_bounds__(THREADS) void seg_mean_sload_kernel(
    const int* __restrict__ tokens,
    const int* __restrict__ seg_start,  // [NSEG+1]
    const float* __restrict__ emb,      // [V, D]
    const float* __restrict__ pos,      // [S, D]
    float* __restrict__ out)            // [B*S, D]
{
    __shared__ float s_pos[DD];         // 4 KB: the block's shared pos row

    const int tid = threadIdx.x;
    const int bg  = blockIdx.x >> 9;    // 0..3  (b-group of 16 batches)
    const int s   = blockIdx.x & (SS - 1);

    // stage pos[s] once per block (shared by 16 segments)
    if (tid < DD / 4) {
        reinterpret_cast<f32x4*>(s_pos)[tid] =
            reinterpret_cast<const f32x4*>(pos + (size_t)s * DD)[tid];
    }
    __syncthreads();

    const int wave = tid >> 6;          // 0..15
    const int lane = tid & 63;
    // wave-uniform seg pinned to SGPR: seg_start/tokens go via s_load (scalar pipe)
    const int seg = __builtin_amdgcn_readfirstlane((bg * WPB + wave) * SS + s);
    const int d0  = lane * 4;

    const int lo = seg_start[seg];
    const int hi = seg_start[seg + 1];

    f32x4 a0 = (f32x4)(0.f), a1 = (f32x4)(0.f), a2 = (f32x4)(0.f), a3 = (f32x4)(0.f);
    for (int t = lo; t < hi; ++t) {
        const int tok = tokens[t];               // SGPR index -> s_load (K$ hit)
        const float* erow = emb + (size_t)tok * DD + d0;
        a0 += *reinterpret_cast<const f32x4*>(erow);
        a1 += *reinterpret_cast<const f32x4*>(erow + 256);
        a2 += *reinterpret_cast<const f32x4*>(erow + 512);
        a3 += *reinterpret_cast<const f32x4*>(erow + 768);
    }

    const int cnt = hi - lo;
    const float inv = (cnt > 0) ? (1.0f / (float)cnt) : 0.0f;

    // pos from LDS (ds_read, lgkm pipe — no VMEM)
    const f32x4 p0 = *reinterpret_cast<const f32x4*>(s_pos + d0);
    const f32x4 p1 = *reinterpret_cast<const f32x4*>(s_pos + d0 + 256);
    const f32x4 p2 = *reinterpret_cast<const f32x4*>(s_pos + d0 + 512);
    const f32x4 p3 = *reinterpret_cast<const f32x4*>(s_pos + d0 + 768);

    f32x4 o0 = a0 * inv + p0;
    f32x4 o1 = a1 * inv + p1;
    f32x4 o2 = a2 * inv + p2;
    f32x4 o3 = a3 * inv + p3;

    float* orow = out + (size_t)seg * DD + d0;
    __builtin_nontemporal_store(o0, reinterpret_cast<f32x4*>(orow));
    __builtin_nontemporal_store(o1, reinterpret_cast<f32x4*>(orow + 256));
    __builtin_nontemporal_store(o2, reinterpret_cast<f32x4*>(orow + 512));
    __builtin_nontemporal_store(o3, reinterpret_cast<f32x4*>(orow + 768));
}

// ---------- Fallback (ws too small): binary-search kernel ----------
__device__ __forceinline__ int lower_bound_dev(const int* __restrict__ a, int n, int key) {
    int lo = 0, hi = n;
    while (lo < hi) {
        int mid = (lo + hi) >> 1;
        if (a[mid] < key) lo = mid + 1; else hi = mid;
    }
    return lo;
}

__global__ __launch_bounds__(256) void seg_mean_embed_bsearch_kernel(
    const int* __restrict__ tokens,
    const int* __restrict__ seg_ids,
    const float* __restrict__ emb,
    const float* __restrict__ pos,
    float* __restrict__ out,
    int T)
{
    const int seg = blockIdx.x;
    const int lo = lower_bound_dev(seg_ids, T, seg);
    const int hi = lower_bound_dev(seg_ids, T, seg + 1);
    const int d = threadIdx.x * 4;

    f32x4 acc = (f32x4)(0.f);
    for (int t = lo; t < hi; ++t) {
        const int tok = tokens[t];
        acc += *reinterpret_cast<const f32x4*>(emb + (size_t)tok * DD + d);
    }
    const int cnt = hi - lo;
    const float inv = (cnt > 0) ? (1.0f / (float)cnt) : 0.0f;
    const int s = seg & (SS - 1);
    const f32x4 p = *reinterpret_cast<const f32x4*>(pos + (size_t)s * DD + d);
    f32x4 o = acc * inv + p;
    *reinterpret_cast<f32x4*>(out + (size_t)seg * DD + d) = o;
}

extern "C" void kernel_launch(void* const* d_in, const int* in_sizes, int n_in,
                              void* d_out, int out_size, void* d_ws, size_t ws_size,
                              hipStream_t stream) {
    const int*   tokens  = (const int*)d_in[0];
    const int*   seg_ids = (const int*)d_in[1];
    const float* emb     = (const float*)d_in[2];
    const float* pos     = (const float*)d_in[3];
    float*       out     = (float*)d_out;
    const int T = in_sizes[0];

    const size_t need = (size_t)(NSEG + 1) * sizeof(int);
    if (ws_size >= need) {
        int* seg_start = (int*)d_ws;
        fill_bounds_kernel<<<(T + 255) / 256, 256, 0, stream>>>(seg_ids, seg_start, T);
        seg_mean_sload_kernel<<<GRID, THREADS, 0, stream>>>(tokens, seg_start, emb, pos, out);
    } else {
        seg_mean_embed_bsearch_kernel<<<NSEG, 256, 0, stream>>>(tokens, seg_ids, emb, pos, out, T);
    }
}